// Round 9
// baseline (581.202 us; speedup 1.0000x reference)
//
#include <hip/hip_runtime.h>

#define NN 100000
#define NE 1600000
#define NLB 256            // lsort chunks (full-GPU block count)
#define CHUNK (NE / NLB)   // 6250 edges per chunk
#define NB 196             // dst buckets (dst >> 9), 196*512 >= NN
#define BN 512             // nodes per bucket
#define NTILE (NN / 32)    // 3125 exact 32-node tiles (mid/final)
#define NFT 1563           // 64-node front-GEMM tiles (1562*64+32 = NN)

__device__ __forceinline__ float bf2f(unsigned short u) {
    return __uint_as_float(((unsigned int)u) << 16);
}
__device__ __forceinline__ unsigned short f2bf(float f) {
    unsigned int u = __float_as_uint(f);
    return (unsigned short)((u + 0x7FFFu + ((u >> 16) & 1u)) >> 16);
}

// ================= fused front end: blocks [0,NLB) sort edges, rest do z1=x@W1
// R16: GEMM half reads x global-direct into register chunks (no xs staging,
// no stage barrier), 2 nodes/thread over 64-node tiles; LDS 19 KB.
__global__ __launch_bounds__(256) void k_front(const int* __restrict__ src,
                                               const int* __restrict__ dst,
                                               int* __restrict__ pairs,
                                               int* __restrict__ tstart,
                                               int* __restrict__ tcnt,
                                               int* __restrict__ btot,
                                               const float* __restrict__ x,
                                               const float* __restrict__ W1,
                                               unsigned short* __restrict__ z1) {
    __shared__ float Ws[128 * 32];     // 16 KB
    __shared__ int cnt[NB];            // lsort
    __shared__ int sc[256];
    __shared__ int cur[NB];
    int tid = threadIdx.x;
    if (blockIdx.x < NLB) {
        int blk = blockIdx.x;
        int e0 = blk * CHUNK;
        for (int i = tid; i < NB; i += 256) cnt[i] = 0;
        __syncthreads();
        for (int i = tid; i < CHUNK; i += 256) atomicAdd(&cnt[dst[e0 + i] >> 9], 1);
        __syncthreads();
        sc[tid] = (tid < NB) ? cnt[tid] : 0;
        __syncthreads();
        for (int off = 1; off < 256; off <<= 1) {
            int v = (tid >= off) ? sc[tid - off] : 0;
            __syncthreads();
            sc[tid] += v;
            __syncthreads();
        }
        if (tid < NB) {
            int excl = sc[tid] - cnt[tid];
            cur[tid] = excl;
            tstart[blk * NB + tid] = excl;
            tcnt[blk * NB + tid]   = cnt[tid];
            atomicAdd(&btot[tid], cnt[tid]);
        }
        __syncthreads();
        for (int i = tid; i < CHUNK; i += 256) {
            int d = dst[e0 + i], s = src[e0 + i];
            int p = atomicAdd(&cur[d >> 9], 1);
            pairs[e0 + p] = ((d & (BN - 1)) << 17) | s;
        }
    } else {
        // ---------------- z1 = x @ W1, bf16 out; 64-node tile, 2 nodes/thread
        int base = (blockIdx.x - NLB) * 64;
        for (int i = tid; i < 1024; i += 256) {
            float4 w = ((const float4*)W1)[i];
            float* d = &Ws[i * 4];
            d[0] = w.x; d[1] = w.y; d[2] = w.z; d[3] = w.w;
        }
        __syncthreads();
        int pair = tid >> 3;           // 0..31
        int j0   = (tid & 7) * 4;
        int na = base + pair * 2;
        int nb = na + 1;
        int ca = (na < NN) ? na : (NN - 1);   // clamp tail tile
        int cb = (nb < NN) ? nb : (NN - 1);
        const float4* xa4 = (const float4*)(x + (size_t)ca * 128);
        const float4* xb4 = (const float4*)(x + (size_t)cb * 128);
        float a00=0,a01=0,a02=0,a03=0,a10=0,a11=0,a12=0,a13=0;
        #pragma unroll
        for (int c = 0; c < 4; c++) {
            float4 ra[8], rb[8];
            #pragma unroll
            for (int i = 0; i < 8; i++) { ra[i] = xa4[c * 8 + i]; rb[i] = xb4[c * 8 + i]; }
            #pragma unroll
            for (int i = 0; i < 8; i++) {
                #pragma unroll
                for (int kk = 0; kk < 4; kk++) {
                    int k = c * 32 + i * 4 + kk;
                    float4 w = *(const float4*)&Ws[k * 32 + j0];
                    float xv_a = (&ra[i].x)[kk];
                    float xv_b = (&rb[i].x)[kk];
                    a00 = fmaf(xv_a, w.x, a00); a01 = fmaf(xv_a, w.y, a01);
                    a02 = fmaf(xv_a, w.z, a02); a03 = fmaf(xv_a, w.w, a03);
                    a10 = fmaf(xv_b, w.x, a10); a11 = fmaf(xv_b, w.y, a11);
                    a12 = fmaf(xv_b, w.z, a12); a13 = fmaf(xv_b, w.w, a13);
                }
            }
        }
        ushort4 oa = { f2bf(a00), f2bf(a01), f2bf(a02), f2bf(a03) };
        ushort4 ob = { f2bf(a10), f2bf(a11), f2bf(a12), f2bf(a13) };
        if (na < NN) *(ushort4*)&z1[(size_t)na * 32 + j0] = oa;
        if (nb < NN) *(ushort4*)&z1[(size_t)nb * 32 + j0] = ob;
    }
}

// ============================= pass 2: per-bucket CSR via wave segment-walks
__global__ __launch_bounds__(1024) void k_build(const int* __restrict__ pairs,
                                                const int* __restrict__ tstart,
                                                const int* __restrict__ tcnt,
                                                const int* __restrict__ btot,
                                                int* __restrict__ csr,
                                                int* __restrict__ row) {
    __shared__ int segS[NLB], segL[NLB];
    __shared__ int ncnt[BN];
    __shared__ int nbase[BN + 1];
    __shared__ int sc[256];
    __shared__ int sc2[256];
    __shared__ int base_s;
    int tid = threadIdx.x, b = blockIdx.x;

    if (tid < 256) sc2[tid] = (tid < NB) ? btot[tid] : 0;
    __syncthreads();
    for (int off = 1; off < 256; off <<= 1) {
        int v = 0;
        if (tid < 256 && tid >= off) v = sc2[tid - off];
        __syncthreads();
        if (tid < 256) sc2[tid] += v;
        __syncthreads();
    }
    if (tid == 0) base_s = (b == 0) ? 0 : sc2[b - 1];
    if (tid < NLB) {
        segS[tid] = tid * CHUNK + tstart[tid * NB + b];
        segL[tid] = tcnt[tid * NB + b];
    }
    for (int i = tid; i < BN; i += 1024) ncnt[i] = 0;
    __syncthreads();

    int wave = tid >> 6, lane = tid & 63;
    for (int s = wave; s < NLB; s += 16) {
        int st = segS[s], len = segL[s];
        for (int i = lane; i < len; i += 64)
            atomicAdd(&ncnt[pairs[st + i] >> 17], 1);
    }
    __syncthreads();

    int c0 = 0, c1 = 0, tsum = 0;
    if (tid < 256) { c0 = ncnt[2 * tid]; c1 = ncnt[2 * tid + 1]; tsum = c0 + c1; sc[tid] = tsum; }
    __syncthreads();
    for (int off = 1; off < 256; off <<= 1) {
        int v = 0;
        if (tid < 256 && tid >= off) v = sc[tid - off];
        __syncthreads();
        if (tid < 256) sc[tid] += v;
        __syncthreads();
    }
    if (tid < 256) {
        int excl = sc[tid] - tsum;
        nbase[2 * tid]     = excl;
        nbase[2 * tid + 1] = excl + c0;
    }
    __syncthreads();

    int base = base_s;
    if (tid < BN) {
        int n = b * BN + tid;
        if (n < NN) row[n] = base + nbase[tid];
        ncnt[tid] = 0;
    }
    if (b == NB - 1 && tid == 0) row[NN] = NE;
    __syncthreads();

    for (int s = wave; s < NLB; s += 16) {
        int st = segS[s], len = segL[s];
        for (int i = lane; i < len; i += 64) {
            int p = pairs[st + i];
            int ln = p >> 17;
            int pos = atomicAdd(&ncnt[ln], 1);
            csr[base + nbase[ln] + pos] = p & 0x1FFFF;
        }
    }
}

// ================================================================ gathers
// One wave = one dst node; uint2/lane, 8 lanes cover a 64 B z row -> 8 edges
// per load instruction. 3-round butterfly shfl_xor reduce over edge slots.
// (R14-proven version.)
__global__ __launch_bounds__(256) void k_gather32(const int* __restrict__ row,
                                                  const int* __restrict__ csr,
                                                  const unsigned short* __restrict__ z,
                                                  float* __restrict__ agg) {
    int n = blockIdx.x * 4 + (threadIdx.x >> 6);
    int lane = threadIdx.x & 63;
    int g = lane >> 3;          // edge slot 0..7
    int q = lane & 7;           // features 4q..4q+3
    int j = row[n], e = row[n + 1];
    float a0 = 0.f, a1 = 0.f, a2 = 0.f, a3 = 0.f;
#define G32_BODY(J) { \
        int idx_ = csr[(J) + g]; \
        uint2 v_ = *(const uint2*)(z + (size_t)idx_ * 32 + q * 4); \
        a0 += __uint_as_float(v_.x << 16); \
        a1 += __uint_as_float(v_.x & 0xFFFF0000u); \
        a2 += __uint_as_float(v_.y << 16); \
        a3 += __uint_as_float(v_.y & 0xFFFF0000u); }
    for (; j + 16 <= e; j += 16) { G32_BODY(j) G32_BODY(j + 8) }
    if (j + 8 <= e) { G32_BODY(j) j += 8; }
    int rem = e - j;
    if (rem > 0) {
        int gg = (g < rem) ? g : (rem - 1);     // idle slots re-read a hot line
        int idx_ = csr[j + gg];
        uint2 v_ = *(const uint2*)(z + (size_t)idx_ * 32 + q * 4);
        if (g < rem) {
            a0 += __uint_as_float(v_.x << 16);
            a1 += __uint_as_float(v_.x & 0xFFFF0000u);
            a2 += __uint_as_float(v_.y << 16);
            a3 += __uint_as_float(v_.y & 0xFFFF0000u);
        }
    }
#undef G32_BODY
    #pragma unroll
    for (int m = 8; m < 64; m <<= 1) {
        a0 += __shfl_xor(a0, m);
        a1 += __shfl_xor(a1, m);
        a2 += __shfl_xor(a2, m);
        a3 += __shfl_xor(a3, m);
    }
    if (g == 0) *(float4*)&agg[(size_t)n * 32 + q * 4] = make_float4(a0, a1, a2, a3);
}

// gather64: uint4/lane (16 B), 8 lanes cover a 128 B z2 row -> 8 edges per
// load instruction; 8 accumulators per lane; 3-round butterfly reduce.
__global__ __launch_bounds__(256) void k_gather64(const int* __restrict__ row,
                                                  const int* __restrict__ csr,
                                                  const unsigned short* __restrict__ z,
                                                  float* __restrict__ agg) {
    int n = blockIdx.x * 4 + (threadIdx.x >> 6);
    int lane = threadIdx.x & 63;
    int g = lane >> 3;          // edge slot 0..7
    int q = lane & 7;           // features 8q..8q+7
    int j = row[n], e = row[n + 1];
    float a0 = 0.f, a1 = 0.f, a2 = 0.f, a3 = 0.f;
    float a4 = 0.f, a5 = 0.f, a6 = 0.f, a7 = 0.f;
#define G64B(J) { \
        int idx_ = csr[(J) + g]; \
        uint4 v_ = *(const uint4*)(z + (size_t)idx_ * 64 + q * 8); \
        a0 += __uint_as_float(v_.x << 16); a1 += __uint_as_float(v_.x & 0xFFFF0000u); \
        a2 += __uint_as_float(v_.y << 16); a3 += __uint_as_float(v_.y & 0xFFFF0000u); \
        a4 += __uint_as_float(v_.z << 16); a5 += __uint_as_float(v_.z & 0xFFFF0000u); \
        a6 += __uint_as_float(v_.w << 16); a7 += __uint_as_float(v_.w & 0xFFFF0000u); }
    for (; j + 16 <= e; j += 16) { G64B(j) G64B(j + 8) }
    if (j + 8 <= e) { G64B(j) j += 8; }
    int rem = e - j;
    if (rem > 0) {
        int gg = (g < rem) ? g : (rem - 1);
        int idx_ = csr[j + gg];
        uint4 v_ = *(const uint4*)(z + (size_t)idx_ * 64 + q * 8);
        if (g < rem) {
            a0 += __uint_as_float(v_.x << 16); a1 += __uint_as_float(v_.x & 0xFFFF0000u);
            a2 += __uint_as_float(v_.y << 16); a3 += __uint_as_float(v_.y & 0xFFFF0000u);
            a4 += __uint_as_float(v_.z << 16); a5 += __uint_as_float(v_.z & 0xFFFF0000u);
            a6 += __uint_as_float(v_.w << 16); a7 += __uint_as_float(v_.w & 0xFFFF0000u);
        }
    }
#undef G64B
    #pragma unroll
    for (int m = 8; m < 64; m <<= 1) {
        a0 += __shfl_xor(a0, m); a1 += __shfl_xor(a1, m);
        a2 += __shfl_xor(a2, m); a3 += __shfl_xor(a3, m);
        a4 += __shfl_xor(a4, m); a5 += __shfl_xor(a5, m);
        a6 += __shfl_xor(a6, m); a7 += __shfl_xor(a7, m);
    }
    if (g == 0) {
        *(float4*)&agg[(size_t)n * 64 + q * 8]     = make_float4(a0, a1, a2, a3);
        *(float4*)&agg[(size_t)n * 64 + q * 8 + 4] = make_float4(a4, a5, a6, a7);
    }
}

// --- fused: t = relu(z1+agg1+b1); h = relu(t@W2+b2); z2 = h@W3 (bf16 in/out)
__global__ __launch_bounds__(256) void k_mid(const unsigned short* __restrict__ z1,
                                             const float* __restrict__ agg1,
                                             const float* __restrict__ b1,
                                             const float* __restrict__ W2,
                                             const float* __restrict__ b2,
                                             const float* __restrict__ W3,
                                             unsigned short* __restrict__ z2) {
    __shared__ float W2s[32 * 64];
    __shared__ float W3s[64 * 64];
    __shared__ float ts[32][33];
    __shared__ float hs[32 * 68];
    __shared__ float b1s[32], b2s[64];
    int tid = threadIdx.x;
    int base = blockIdx.x * 32;
    for (int i = tid; i < 512; i += 256) {
        float4 w = ((const float4*)W2)[i];
        float* d = &W2s[i * 4];
        d[0] = w.x; d[1] = w.y; d[2] = w.z; d[3] = w.w;
    }
    for (int i = tid; i < 1024; i += 256) {
        float4 w = ((const float4*)W3)[i];
        float* d = &W3s[i * 4];
        d[0] = w.x; d[1] = w.y; d[2] = w.z; d[3] = w.w;
    }
    if (tid < 32) b1s[tid] = b1[tid];
    if (tid >= 64 && tid < 128) b2s[tid - 64] = b2[tid - 64];
    __syncthreads();
    #pragma unroll
    for (int r = 0; r < 4; r++) {
        int idx = tid + 256 * r;
        int n = idx >> 5, f = idx & 31;
        ts[n][f] = fmaxf(bf2f(z1[(size_t)base * 32 + idx]) + agg1[(size_t)base * 32 + idx] + b1s[f], 0.f);
    }
    __syncthreads();
    int n2 = tid >> 4;
    int j0 = (tid & 15) * 4;
    int na = 2 * n2, nb = 2 * n2 + 1;
    {
        float a00=0,a01=0,a02=0,a03=0,a10=0,a11=0,a12=0,a13=0;
        #pragma unroll 8
        for (int k = 0; k < 32; k++) {
            float t0 = ts[na][k], t1 = ts[nb][k];
            float4 w = *(const float4*)&W2s[k * 64 + j0];
            a00=fmaf(t0,w.x,a00); a01=fmaf(t0,w.y,a01); a02=fmaf(t0,w.z,a02); a03=fmaf(t0,w.w,a03);
            a10=fmaf(t1,w.x,a10); a11=fmaf(t1,w.y,a11); a12=fmaf(t1,w.z,a12); a13=fmaf(t1,w.w,a13);
        }
        *(float4*)&hs[na * 68 + j0] = make_float4(fmaxf(a00+b2s[j0],0.f), fmaxf(a01+b2s[j0+1],0.f),
                                                  fmaxf(a02+b2s[j0+2],0.f), fmaxf(a03+b2s[j0+3],0.f));
        *(float4*)&hs[nb * 68 + j0] = make_float4(fmaxf(a10+b2s[j0],0.f), fmaxf(a11+b2s[j0+1],0.f),
                                                  fmaxf(a12+b2s[j0+2],0.f), fmaxf(a13+b2s[j0+3],0.f));
    }
    __syncthreads();
    {
        float a00=0,a01=0,a02=0,a03=0,a10=0,a11=0,a12=0,a13=0;
        #pragma unroll 8
        for (int k = 0; k < 64; k++) {
            float h0 = hs[na * 68 + k], h1 = hs[nb * 68 + k];
            float4 w = *(const float4*)&W3s[k * 64 + j0];
            a00=fmaf(h0,w.x,a00); a01=fmaf(h0,w.y,a01); a02=fmaf(h0,w.z,a02); a03=fmaf(h0,w.w,a03);
            a10=fmaf(h1,w.x,a10); a11=fmaf(h1,w.y,a11); a12=fmaf(h1,w.z,a12); a13=fmaf(h1,w.w,a13);
        }
        ushort4 oa = { f2bf(a00), f2bf(a01), f2bf(a02), f2bf(a03) };
        ushort4 ob = { f2bf(a10), f2bf(a11), f2bf(a12), f2bf(a13) };
        *(ushort4*)&z2[(size_t)(base + na) * 64 + j0] = oa;
        *(ushort4*)&z2[(size_t)(base + nb) * 64 + j0] = ob;
    }
}

// --------- final: u = relu(z2+agg2+b3); out = relu(u@W4+b4) -> f32 + pooled
__global__ __launch_bounds__(256) void k_final(const unsigned short* __restrict__ z2,
                                               const float* __restrict__ agg2,
                                               const float* __restrict__ b3,
                                               const float* __restrict__ W4,
                                               const float* __restrict__ b4,
                                               float* __restrict__ out,
                                               float* __restrict__ gpool) {
    __shared__ float W4s[64 * 64];
    __shared__ float us[32 * 68];
    __shared__ float b3s[64], b4s[64], pool[64];
    int tid = threadIdx.x;
    int base = blockIdx.x * 32;
    for (int i = tid; i < 1024; i += 256) {
        float4 w = ((const float4*)W4)[i];
        float* d = &W4s[i * 4];
        d[0] = w.x; d[1] = w.y; d[2] = w.z; d[3] = w.w;
    }
    if (tid < 64) { b3s[tid] = b3[tid]; pool[tid] = 0.f; }
    if (tid >= 64 && tid < 128) b4s[tid - 64] = b4[tid - 64];
    __syncthreads();
    #pragma unroll
    for (int r = 0; r < 8; r++) {
        int idx = tid + 256 * r;
        int n = idx >> 6, f = idx & 63;
        us[n * 68 + f] = fmaxf(bf2f(z2[(size_t)base * 64 + idx]) + agg2[(size_t)base * 64 + idx] + b3s[f], 0.f);
    }
    __syncthreads();
    int n2 = tid >> 4;
    int j0 = (tid & 15) * 4;
    int na = 2 * n2, nb = 2 * n2 + 1;
    float a00=0,a01=0,a02=0,a03=0,a10=0,a11=0,a12=0,a13=0;
    #pragma unroll 8
    for (int k = 0; k < 64; k++) {
        float u0 = us[na * 68 + k], u1 = us[nb * 68 + k];
        float4 w = *(const float4*)&W4s[k * 64 + j0];
        a00=fmaf(u0,w.x,a00); a01=fmaf(u0,w.y,a01); a02=fmaf(u0,w.z,a02); a03=fmaf(u0,w.w,a03);
        a10=fmaf(u1,w.x,a10); a11=fmaf(u1,w.y,a11); a12=fmaf(u1,w.z,a12); a13=fmaf(u1,w.w,a13);
    }
    float v00=fmaxf(a00+b4s[j0],0.f), v01=fmaxf(a01+b4s[j0+1],0.f);
    float v02=fmaxf(a02+b4s[j0+2],0.f), v03=fmaxf(a03+b4s[j0+3],0.f);
    float v10=fmaxf(a10+b4s[j0],0.f), v11=fmaxf(a11+b4s[j0+1],0.f);
    float v12=fmaxf(a12+b4s[j0+2],0.f), v13=fmaxf(a13+b4s[j0+3],0.f);
    *(float4*)&out[(size_t)(base + na) * 64 + j0] = make_float4(v00, v01, v02, v03);
    *(float4*)&out[(size_t)(base + nb) * 64 + j0] = make_float4(v10, v11, v12, v13);
    __syncthreads();
    atomicAdd(&pool[j0 + 0], v00 + v10);
    atomicAdd(&pool[j0 + 1], v01 + v11);
    atomicAdd(&pool[j0 + 2], v02 + v12);
    atomicAdd(&pool[j0 + 3], v03 + v13);
    __syncthreads();
    if (tid < 64) unsafeAtomicAdd(&gpool[(blockIdx.x & 7) * 64 + tid], pool[tid]);
}

__global__ void k_pool(const float* __restrict__ gpool, float* __restrict__ out) {
    int t = threadIdx.x;
    if (t < 64) {
        float s = 0.f;
        #pragma unroll
        for (int k = 0; k < 8; k++) s += gpool[k * 64 + t];
        out[(size_t)NN * 64 + t] = s * (1.0f / NN);
    }
}

extern "C" void kernel_launch(void* const* d_in, const int* in_sizes, int n_in,
                              void* d_out, int out_size, void* d_ws, size_t ws_size,
                              hipStream_t stream) {
    const float* x  = (const float*)d_in[0];
    const int*   ei = (const int*)d_in[1];
    const float* W1 = (const float*)d_in[3];
    const float* b1 = (const float*)d_in[4];
    const float* W2 = (const float*)d_in[5];
    const float* b2 = (const float*)d_in[6];
    const float* W3 = (const float*)d_in[7];
    const float* b3 = (const float*)d_in[8];
    const float* W4 = (const float*)d_in[9];
    const float* b4 = (const float*)d_in[10];
    float* out = (float*)d_out;

    // ws (4B slots): tstart[NLB*NB] tcnt[NLB*NB] btot[196] gpool[512 (8 shards)]
    //   row[NN+4] csr[NE]
    //   then: pairs[NE] | z1b[NN*16] | agg1[NN*32]   (sum = NN*64 slots)
    //         ^-- agg2[NN*64 f32] exactly overlays these three
    //   then: z2b[NN*32 slots].   total ~46 MB
    int*   ip     = (int*)d_ws;
    int*   tstart = ip;                          // NLB*NB = 50176
    int*   tcnt   = ip + NLB * NB;               // 50176
    int*   btot   = ip + 2 * NLB * NB;           // 196
    float* gpool  = (float*)(ip + 2 * NLB * NB + 196);  // 512
    int*   row    = ip + 2 * NLB * NB + 196 + 512;      // NN+4 (row[NN]=NE)
    int*   csr    = row + NN + 4;                // NE
    int*   pairs  = csr + NE;                    // NE
    unsigned short* z1b = (unsigned short*)(pairs + NE);        // NN*32 bf16
    float* agg1   = (float*)(pairs + NE + NN * 16);             // NN*32 f32
    float* agg2   = (float*)pairs;               // overlays pairs+z1b+agg1
    unsigned short* z2b = (unsigned short*)(agg1 + (size_t)NN * 32);  // NN*64 bf16
    const int* src = ei;
    const int* dst = ei + NE;

    hipMemsetAsync(btot, 0, (196 + 512) * sizeof(int), stream);  // btot + gpool
    k_front<<<NLB + NFT, 256, 0, stream>>>(src, dst, pairs, tstart, tcnt, btot, x, W1, z1b);
    k_build<<<NB, 1024, 0, stream>>>(pairs, tstart, tcnt, btot, csr, row);
    k_gather32<<<NN / 4, 256, 0, stream>>>(row, csr, z1b, agg1);
    k_mid<<<NTILE, 256, 0, stream>>>(z1b, agg1, b1, W2, b2, W3, z2b);
    k_gather64<<<NN / 4, 256, 0, stream>>>(row, csr, z2b, agg2);
    k_final<<<NTILE, 256, 0, stream>>>(z2b, agg2, b3, W4, b4, out, gpool);
    k_pool<<<1, 64, 0, stream>>>(gpool, out);
}

// Round 10
// 300.570 us; speedup vs baseline: 1.9337x; 1.9337x over previous
//
#include <hip/hip_runtime.h>

#define NN 100000
#define NE 1600000
#define NLB 256            // lsort chunks (full-GPU block count)
#define CHUNK (NE / NLB)   // 6250 edges per chunk
#define NB 196             // dst buckets (dst >> 9), 196*512 >= NN
#define BN 512             // nodes per bucket
#define NTILE (NN / 32)    // 3125 exact 32-node tiles (mid/final)
#define NFT 1563           // 64-node front-GEMM tiles (1562*64+32 = NN)

__device__ __forceinline__ float bf2f(unsigned short u) {
    return __uint_as_float(((unsigned int)u) << 16);
}
__device__ __forceinline__ unsigned short f2bf(float f) {
    unsigned int u = __float_as_uint(f);
    return (unsigned short)((u + 0x7FFFu + ((u >> 16) & 1u)) >> 16);
}

// ================= fused front end: blocks [0,NLB) sort edges, rest do z1=x@W1
// R17: register-GEMM k_front with the spill fixed — outer chunk loop is
// unroll 1 so only one chunk's ra[8]/rb[8] (64 VGPR) is live at a time.
// (R15's full unroll made all 4 chunks live -> 256 VGPR -> 339 MB scratch.)
__global__ __launch_bounds__(256) void k_front(const int* __restrict__ src,
                                               const int* __restrict__ dst,
                                               int* __restrict__ pairs,
                                               int* __restrict__ tstart,
                                               int* __restrict__ tcnt,
                                               int* __restrict__ btot,
                                               const float* __restrict__ x,
                                               const float* __restrict__ W1,
                                               unsigned short* __restrict__ z1) {
    __shared__ float Ws[128 * 32];     // 16 KB
    __shared__ int cnt[NB];            // lsort
    __shared__ int sc[256];
    __shared__ int cur[NB];
    int tid = threadIdx.x;
    if (blockIdx.x < NLB) {
        int blk = blockIdx.x;
        int e0 = blk * CHUNK;
        for (int i = tid; i < NB; i += 256) cnt[i] = 0;
        __syncthreads();
        for (int i = tid; i < CHUNK; i += 256) atomicAdd(&cnt[dst[e0 + i] >> 9], 1);
        __syncthreads();
        sc[tid] = (tid < NB) ? cnt[tid] : 0;
        __syncthreads();
        for (int off = 1; off < 256; off <<= 1) {
            int v = (tid >= off) ? sc[tid - off] : 0;
            __syncthreads();
            sc[tid] += v;
            __syncthreads();
        }
        if (tid < NB) {
            int excl = sc[tid] - cnt[tid];
            cur[tid] = excl;
            tstart[blk * NB + tid] = excl;
            tcnt[blk * NB + tid]   = cnt[tid];
            atomicAdd(&btot[tid], cnt[tid]);
        }
        __syncthreads();
        for (int i = tid; i < CHUNK; i += 256) {
            int d = dst[e0 + i], s = src[e0 + i];
            int p = atomicAdd(&cur[d >> 9], 1);
            pairs[e0 + p] = ((d & (BN - 1)) << 17) | s;
        }
    } else {
        // ---------------- z1 = x @ W1, bf16 out; 64-node tile, 2 nodes/thread
        int base = (blockIdx.x - NLB) * 64;
        for (int i = tid; i < 1024; i += 256) {
            float4 w = ((const float4*)W1)[i];
            float* d = &Ws[i * 4];
            d[0] = w.x; d[1] = w.y; d[2] = w.z; d[3] = w.w;
        }
        __syncthreads();
        int pair = tid >> 3;           // 0..31
        int j0   = (tid & 7) * 4;
        int na = base + pair * 2;
        int nb = na + 1;
        int ca = (na < NN) ? na : (NN - 1);   // clamp tail tile
        int cb = (nb < NN) ? nb : (NN - 1);
        const float4* xa4 = (const float4*)(x + (size_t)ca * 128);
        const float4* xb4 = (const float4*)(x + (size_t)cb * 128);
        float a00=0,a01=0,a02=0,a03=0,a10=0,a11=0,a12=0,a13=0;
        #pragma unroll 1
        for (int c = 0; c < 4; c++) {
            float4 ra[8], rb[8];
            #pragma unroll
            for (int i = 0; i < 8; i++) { ra[i] = xa4[c * 8 + i]; rb[i] = xb4[c * 8 + i]; }
            #pragma unroll
            for (int i = 0; i < 8; i++) {
                #pragma unroll
                for (int kk = 0; kk < 4; kk++) {
                    int k = c * 32 + i * 4 + kk;
                    float4 w = *(const float4*)&Ws[k * 32 + j0];
                    float xv_a = (&ra[i].x)[kk];
                    float xv_b = (&rb[i].x)[kk];
                    a00 = fmaf(xv_a, w.x, a00); a01 = fmaf(xv_a, w.y, a01);
                    a02 = fmaf(xv_a, w.z, a02); a03 = fmaf(xv_a, w.w, a03);
                    a10 = fmaf(xv_b, w.x, a10); a11 = fmaf(xv_b, w.y, a11);
                    a12 = fmaf(xv_b, w.z, a12); a13 = fmaf(xv_b, w.w, a13);
                }
            }
        }
        ushort4 oa = { f2bf(a00), f2bf(a01), f2bf(a02), f2bf(a03) };
        ushort4 ob = { f2bf(a10), f2bf(a11), f2bf(a12), f2bf(a13) };
        if (na < NN) *(ushort4*)&z1[(size_t)na * 32 + j0] = oa;
        if (nb < NN) *(ushort4*)&z1[(size_t)nb * 32 + j0] = ob;
    }
}

// ============================= pass 2: per-bucket CSR via wave segment-walks
__global__ __launch_bounds__(1024) void k_build(const int* __restrict__ pairs,
                                                const int* __restrict__ tstart,
                                                const int* __restrict__ tcnt,
                                                const int* __restrict__ btot,
                                                int* __restrict__ csr,
                                                int* __restrict__ row) {
    __shared__ int segS[NLB], segL[NLB];
    __shared__ int ncnt[BN];
    __shared__ int nbase[BN + 1];
    __shared__ int sc[256];
    __shared__ int sc2[256];
    __shared__ int base_s;
    int tid = threadIdx.x, b = blockIdx.x;

    if (tid < 256) sc2[tid] = (tid < NB) ? btot[tid] : 0;
    __syncthreads();
    for (int off = 1; off < 256; off <<= 1) {
        int v = 0;
        if (tid < 256 && tid >= off) v = sc2[tid - off];
        __syncthreads();
        if (tid < 256) sc2[tid] += v;
        __syncthreads();
    }
    if (tid == 0) base_s = (b == 0) ? 0 : sc2[b - 1];
    if (tid < NLB) {
        segS[tid] = tid * CHUNK + tstart[tid * NB + b];
        segL[tid] = tcnt[tid * NB + b];
    }
    for (int i = tid; i < BN; i += 1024) ncnt[i] = 0;
    __syncthreads();

    int wave = tid >> 6, lane = tid & 63;
    for (int s = wave; s < NLB; s += 16) {
        int st = segS[s], len = segL[s];
        for (int i = lane; i < len; i += 64)
            atomicAdd(&ncnt[pairs[st + i] >> 17], 1);
    }
    __syncthreads();

    int c0 = 0, c1 = 0, tsum = 0;
    if (tid < 256) { c0 = ncnt[2 * tid]; c1 = ncnt[2 * tid + 1]; tsum = c0 + c1; sc[tid] = tsum; }
    __syncthreads();
    for (int off = 1; off < 256; off <<= 1) {
        int v = 0;
        if (tid < 256 && tid >= off) v = sc[tid - off];
        __syncthreads();
        if (tid < 256) sc[tid] += v;
        __syncthreads();
    }
    if (tid < 256) {
        int excl = sc[tid] - tsum;
        nbase[2 * tid]     = excl;
        nbase[2 * tid + 1] = excl + c0;
    }
    __syncthreads();

    int base = base_s;
    if (tid < BN) {
        int n = b * BN + tid;
        if (n < NN) row[n] = base + nbase[tid];
        ncnt[tid] = 0;
    }
    if (b == NB - 1 && tid == 0) row[NN] = NE;
    __syncthreads();

    for (int s = wave; s < NLB; s += 16) {
        int st = segS[s], len = segL[s];
        for (int i = lane; i < len; i += 64) {
            int p = pairs[st + i];
            int ln = p >> 17;
            int pos = atomicAdd(&ncnt[ln], 1);
            csr[base + nbase[ln] + pos] = p & 0x1FFFF;
        }
    }
}

// ================================================================ gathers
// One wave = one dst node; uint2/lane, 8 lanes cover a 64 B z row -> 8 edges
// per load instruction. 3-round butterfly shfl_xor reduce over edge slots.
__global__ __launch_bounds__(256) void k_gather32(const int* __restrict__ row,
                                                  const int* __restrict__ csr,
                                                  const unsigned short* __restrict__ z,
                                                  float* __restrict__ agg) {
    int n = blockIdx.x * 4 + (threadIdx.x >> 6);
    int lane = threadIdx.x & 63;
    int g = lane >> 3;          // edge slot 0..7
    int q = lane & 7;           // features 4q..4q+3
    int j = row[n], e = row[n + 1];
    float a0 = 0.f, a1 = 0.f, a2 = 0.f, a3 = 0.f;
#define G32_BODY(J) { \
        int idx_ = csr[(J) + g]; \
        uint2 v_ = *(const uint2*)(z + (size_t)idx_ * 32 + q * 4); \
        a0 += __uint_as_float(v_.x << 16); \
        a1 += __uint_as_float(v_.x & 0xFFFF0000u); \
        a2 += __uint_as_float(v_.y << 16); \
        a3 += __uint_as_float(v_.y & 0xFFFF0000u); }
    for (; j + 16 <= e; j += 16) { G32_BODY(j) G32_BODY(j + 8) }
    if (j + 8 <= e) { G32_BODY(j) j += 8; }
    int rem = e - j;
    if (rem > 0) {
        int gg = (g < rem) ? g : (rem - 1);     // idle slots re-read a hot line
        int idx_ = csr[j + gg];
        uint2 v_ = *(const uint2*)(z + (size_t)idx_ * 32 + q * 4);
        if (g < rem) {
            a0 += __uint_as_float(v_.x << 16);
            a1 += __uint_as_float(v_.x & 0xFFFF0000u);
            a2 += __uint_as_float(v_.y << 16);
            a3 += __uint_as_float(v_.y & 0xFFFF0000u);
        }
    }
#undef G32_BODY
    #pragma unroll
    for (int m = 8; m < 64; m <<= 1) {
        a0 += __shfl_xor(a0, m);
        a1 += __shfl_xor(a1, m);
        a2 += __shfl_xor(a2, m);
        a3 += __shfl_xor(a3, m);
    }
    if (g == 0) *(float4*)&agg[(size_t)n * 32 + q * 4] = make_float4(a0, a1, a2, a3);
}

// gather64: uint4/lane (16 B), 8 lanes cover a 128 B z2 row -> 8 edges per
// load instruction; 8 accumulators per lane; 3-round butterfly reduce.
__global__ __launch_bounds__(256) void k_gather64(const int* __restrict__ row,
                                                  const int* __restrict__ csr,
                                                  const unsigned short* __restrict__ z,
                                                  float* __restrict__ agg) {
    int n = blockIdx.x * 4 + (threadIdx.x >> 6);
    int lane = threadIdx.x & 63;
    int g = lane >> 3;          // edge slot 0..7
    int q = lane & 7;           // features 8q..8q+7
    int j = row[n], e = row[n + 1];
    float a0 = 0.f, a1 = 0.f, a2 = 0.f, a3 = 0.f;
    float a4 = 0.f, a5 = 0.f, a6 = 0.f, a7 = 0.f;
#define G64B(J) { \
        int idx_ = csr[(J) + g]; \
        uint4 v_ = *(const uint4*)(z + (size_t)idx_ * 64 + q * 8); \
        a0 += __uint_as_float(v_.x << 16); a1 += __uint_as_float(v_.x & 0xFFFF0000u); \
        a2 += __uint_as_float(v_.y << 16); a3 += __uint_as_float(v_.y & 0xFFFF0000u); \
        a4 += __uint_as_float(v_.z << 16); a5 += __uint_as_float(v_.z & 0xFFFF0000u); \
        a6 += __uint_as_float(v_.w << 16); a7 += __uint_as_float(v_.w & 0xFFFF0000u); }
    for (; j + 16 <= e; j += 16) { G64B(j) G64B(j + 8) }
    if (j + 8 <= e) { G64B(j) j += 8; }
    int rem = e - j;
    if (rem > 0) {
        int gg = (g < rem) ? g : (rem - 1);
        int idx_ = csr[j + gg];
        uint4 v_ = *(const uint4*)(z + (size_t)idx_ * 64 + q * 8);
        if (g < rem) {
            a0 += __uint_as_float(v_.x << 16); a1 += __uint_as_float(v_.x & 0xFFFF0000u);
            a2 += __uint_as_float(v_.y << 16); a3 += __uint_as_float(v_.y & 0xFFFF0000u);
            a4 += __uint_as_float(v_.z << 16); a5 += __uint_as_float(v_.z & 0xFFFF0000u);
            a6 += __uint_as_float(v_.w << 16); a7 += __uint_as_float(v_.w & 0xFFFF0000u);
        }
    }
#undef G64B
    #pragma unroll
    for (int m = 8; m < 64; m <<= 1) {
        a0 += __shfl_xor(a0, m); a1 += __shfl_xor(a1, m);
        a2 += __shfl_xor(a2, m); a3 += __shfl_xor(a3, m);
        a4 += __shfl_xor(a4, m); a5 += __shfl_xor(a5, m);
        a6 += __shfl_xor(a6, m); a7 += __shfl_xor(a7, m);
    }
    if (g == 0) {
        *(float4*)&agg[(size_t)n * 64 + q * 8]     = make_float4(a0, a1, a2, a3);
        *(float4*)&agg[(size_t)n * 64 + q * 8 + 4] = make_float4(a4, a5, a6, a7);
    }
}

// --- fused: t = relu(z1+agg1+b1); h = relu(t@W2+b2); z2 = h@W3 (bf16 in/out)
__global__ __launch_bounds__(256) void k_mid(const unsigned short* __restrict__ z1,
                                             const float* __restrict__ agg1,
                                             const float* __restrict__ b1,
                                             const float* __restrict__ W2,
                                             const float* __restrict__ b2,
                                             const float* __restrict__ W3,
                                             unsigned short* __restrict__ z2) {
    __shared__ float W2s[32 * 64];
    __shared__ float W3s[64 * 64];
    __shared__ float ts[32][33];
    __shared__ float hs[32 * 68];
    __shared__ float b1s[32], b2s[64];
    int tid = threadIdx.x;
    int base = blockIdx.x * 32;
    for (int i = tid; i < 512; i += 256) {
        float4 w = ((const float4*)W2)[i];
        float* d = &W2s[i * 4];
        d[0] = w.x; d[1] = w.y; d[2] = w.z; d[3] = w.w;
    }
    for (int i = tid; i < 1024; i += 256) {
        float4 w = ((const float4*)W3)[i];
        float* d = &W3s[i * 4];
        d[0] = w.x; d[1] = w.y; d[2] = w.z; d[3] = w.w;
    }
    if (tid < 32) b1s[tid] = b1[tid];
    if (tid >= 64 && tid < 128) b2s[tid - 64] = b2[tid - 64];
    __syncthreads();
    #pragma unroll
    for (int r = 0; r < 4; r++) {
        int idx = tid + 256 * r;
        int n = idx >> 5, f = idx & 31;
        ts[n][f] = fmaxf(bf2f(z1[(size_t)base * 32 + idx]) + agg1[(size_t)base * 32 + idx] + b1s[f], 0.f);
    }
    __syncthreads();
    int n2 = tid >> 4;
    int j0 = (tid & 15) * 4;
    int na = 2 * n2, nb = 2 * n2 + 1;
    {
        float a00=0,a01=0,a02=0,a03=0,a10=0,a11=0,a12=0,a13=0;
        #pragma unroll 8
        for (int k = 0; k < 32; k++) {
            float t0 = ts[na][k], t1 = ts[nb][k];
            float4 w = *(const float4*)&W2s[k * 64 + j0];
            a00=fmaf(t0,w.x,a00); a01=fmaf(t0,w.y,a01); a02=fmaf(t0,w.z,a02); a03=fmaf(t0,w.w,a03);
            a10=fmaf(t1,w.x,a10); a11=fmaf(t1,w.y,a11); a12=fmaf(t1,w.z,a12); a13=fmaf(t1,w.w,a13);
        }
        *(float4*)&hs[na * 68 + j0] = make_float4(fmaxf(a00+b2s[j0],0.f), fmaxf(a01+b2s[j0+1],0.f),
                                                  fmaxf(a02+b2s[j0+2],0.f), fmaxf(a03+b2s[j0+3],0.f));
        *(float4*)&hs[nb * 68 + j0] = make_float4(fmaxf(a10+b2s[j0],0.f), fmaxf(a11+b2s[j0+1],0.f),
                                                  fmaxf(a12+b2s[j0+2],0.f), fmaxf(a13+b2s[j0+3],0.f));
    }
    __syncthreads();
    {
        float a00=0,a01=0,a02=0,a03=0,a10=0,a11=0,a12=0,a13=0;
        #pragma unroll 8
        for (int k = 0; k < 64; k++) {
            float h0 = hs[na * 68 + k], h1 = hs[nb * 68 + k];
            float4 w = *(const float4*)&W3s[k * 64 + j0];
            a00=fmaf(h0,w.x,a00); a01=fmaf(h0,w.y,a01); a02=fmaf(h0,w.z,a02); a03=fmaf(h0,w.w,a03);
            a10=fmaf(h1,w.x,a10); a11=fmaf(h1,w.y,a11); a12=fmaf(h1,w.z,a12); a13=fmaf(h1,w.w,a13);
        }
        ushort4 oa = { f2bf(a00), f2bf(a01), f2bf(a02), f2bf(a03) };
        ushort4 ob = { f2bf(a10), f2bf(a11), f2bf(a12), f2bf(a13) };
        *(ushort4*)&z2[(size_t)(base + na) * 64 + j0] = oa;
        *(ushort4*)&z2[(size_t)(base + nb) * 64 + j0] = ob;
    }
}

// --------- final: u = relu(z2+agg2+b3); out = relu(u@W4+b4) -> f32 + pooled
__global__ __launch_bounds__(256) void k_final(const unsigned short* __restrict__ z2,
                                               const float* __restrict__ agg2,
                                               const float* __restrict__ b3,
                                               const float* __restrict__ W4,
                                               const float* __restrict__ b4,
                                               float* __restrict__ out,
                                               float* __restrict__ gpool) {
    __shared__ float W4s[64 * 64];
    __shared__ float us[32 * 68];
    __shared__ float b3s[64], b4s[64], pool[64];
    int tid = threadIdx.x;
    int base = blockIdx.x * 32;
    for (int i = tid; i < 1024; i += 256) {
        float4 w = ((const float4*)W4)[i];
        float* d = &W4s[i * 4];
        d[0] = w.x; d[1] = w.y; d[2] = w.z; d[3] = w.w;
    }
    if (tid < 64) { b3s[tid] = b3[tid]; pool[tid] = 0.f; }
    if (tid >= 64 && tid < 128) b4s[tid - 64] = b4[tid - 64];
    __syncthreads();
    #pragma unroll
    for (int r = 0; r < 8; r++) {
        int idx = tid + 256 * r;
        int n = idx >> 6, f = idx & 63;
        us[n * 68 + f] = fmaxf(bf2f(z2[(size_t)base * 64 + idx]) + agg2[(size_t)base * 64 + idx] + b3s[f], 0.f);
    }
    __syncthreads();
    int n2 = tid >> 4;
    int j0 = (tid & 15) * 4;
    int na = 2 * n2, nb = 2 * n2 + 1;
    float a00=0,a01=0,a02=0,a03=0,a10=0,a11=0,a12=0,a13=0;
    #pragma unroll 8
    for (int k = 0; k < 64; k++) {
        float u0 = us[na * 68 + k], u1 = us[nb * 68 + k];
        float4 w = *(const float4*)&W4s[k * 64 + j0];
        a00=fmaf(u0,w.x,a00); a01=fmaf(u0,w.y,a01); a02=fmaf(u0,w.z,a02); a03=fmaf(u0,w.w,a03);
        a10=fmaf(u1,w.x,a10); a11=fmaf(u1,w.y,a11); a12=fmaf(u1,w.z,a12); a13=fmaf(u1,w.w,a13);
    }
    float v00=fmaxf(a00+b4s[j0],0.f), v01=fmaxf(a01+b4s[j0+1],0.f);
    float v02=fmaxf(a02+b4s[j0+2],0.f), v03=fmaxf(a03+b4s[j0+3],0.f);
    float v10=fmaxf(a10+b4s[j0],0.f), v11=fmaxf(a11+b4s[j0+1],0.f);
    float v12=fmaxf(a12+b4s[j0+2],0.f), v13=fmaxf(a13+b4s[j0+3],0.f);
    *(float4*)&out[(size_t)(base + na) * 64 + j0] = make_float4(v00, v01, v02, v03);
    *(float4*)&out[(size_t)(base + nb) * 64 + j0] = make_float4(v10, v11, v12, v13);
    __syncthreads();
    atomicAdd(&pool[j0 + 0], v00 + v10);
    atomicAdd(&pool[j0 + 1], v01 + v11);
    atomicAdd(&pool[j0 + 2], v02 + v12);
    atomicAdd(&pool[j0 + 3], v03 + v13);
    __syncthreads();
    if (tid < 64) unsafeAtomicAdd(&gpool[(blockIdx.x & 7) * 64 + tid], pool[tid]);
}

__global__ void k_pool(const float* __restrict__ gpool, float* __restrict__ out) {
    int t = threadIdx.x;
    if (t < 64) {
        float s = 0.f;
        #pragma unroll
        for (int k = 0; k < 8; k++) s += gpool[k * 64 + t];
        out[(size_t)NN * 64 + t] = s * (1.0f / NN);
    }
}

extern "C" void kernel_launch(void* const* d_in, const int* in_sizes, int n_in,
                              void* d_out, int out_size, void* d_ws, size_t ws_size,
                              hipStream_t stream) {
    const float* x  = (const float*)d_in[0];
    const int*   ei = (const int*)d_in[1];
    const float* W1 = (const float*)d_in[3];
    const float* b1 = (const float*)d_in[4];
    const float* W2 = (const float*)d_in[5];
    const float* b2 = (const float*)d_in[6];
    const float* W3 = (const float*)d_in[7];
    const float* b3 = (const float*)d_in[8];
    const float* W4 = (const float*)d_in[9];
    const float* b4 = (const float*)d_in[10];
    float* out = (float*)d_out;

    // ws (4B slots): tstart[NLB*NB] tcnt[NLB*NB] btot[196] gpool[512 (8 shards)]
    //   row[NN+4] csr[NE]
    //   then: pairs[NE] | z1b[NN*16] | agg1[NN*32]   (sum = NN*64 slots)
    //         ^-- agg2[NN*64 f32] exactly overlays these three
    //   then: z2b[NN*32 slots].   total ~46 MB
    int*   ip     = (int*)d_ws;
    int*   tstart = ip;                          // NLB*NB = 50176
    int*   tcnt   = ip + NLB * NB;               // 50176
    int*   btot   = ip + 2 * NLB * NB;           // 196
    float* gpool  = (float*)(ip + 2 * NLB * NB + 196);  // 512
    int*   row    = ip + 2 * NLB * NB + 196 + 512;      // NN+4 (row[NN]=NE)
    int*   csr    = row + NN + 4;                // NE
    int*   pairs  = csr + NE;                    // NE
    unsigned short* z1b = (unsigned short*)(pairs + NE);        // NN*32 bf16
    float* agg1   = (float*)(pairs + NE + NN * 16);             // NN*32 f32
    float* agg2   = (float*)pairs;               // overlays pairs+z1b+agg1
    unsigned short* z2b = (unsigned short*)(agg1 + (size_t)NN * 32);  // NN*64 bf16
    const int* src = ei;
    const int* dst = ei + NE;

    hipMemsetAsync(btot, 0, (196 + 512) * sizeof(int), stream);  // btot + gpool
    k_front<<<NLB + NFT, 256, 0, stream>>>(src, dst, pairs, tstart, tcnt, btot, x, W1, z1b);
    k_build<<<NB, 1024, 0, stream>>>(pairs, tstart, tcnt, btot, csr, row);
    k_gather32<<<NN / 4, 256, 0, stream>>>(row, csr, z1b, agg1);
    k_mid<<<NTILE, 256, 0, stream>>>(z1b, agg1, b1, W2, b2, W3, z2b);
    k_gather64<<<NN / 4, 256, 0, stream>>>(row, csr, z2b, agg2);
    k_final<<<NTILE, 256, 0, stream>>>(z2b, agg2, b3, W4, b4, out, gpool);
    k_pool<<<1, 64, 0, stream>>>(gpool, out);
}